// Round 8
// baseline (322.633 us; speedup 1.0000x reference)
//
#include <hip/hip_runtime.h>
#include <hip/hip_bf16.h>
#include <stdint.h>

typedef __bf16 bf16_t;
typedef __bf16 bf16x8 __attribute__((ext_vector_type(8)));
typedef short short8 __attribute__((ext_vector_type(8)));
typedef float f32x4 __attribute__((ext_vector_type(4)));

#define RS512  0.044194173824159216f   // 1/sqrt(512)
#define RS4608 0.014731391274719739f   // 1/sqrt(512*9)

// ---------------- K1: style vector  s[b][c] = (w[b,:] . lw[c,:])/sqrt(512) + lb[c]
__global__ void k_style(const float* __restrict__ w, const float* __restrict__ lw,
                        const float* __restrict__ lb, float* __restrict__ s) {
  int b = blockIdx.y;
  int c = blockIdx.x * 256 + threadIdx.x;
  const float4* wr = (const float4*)(w + b * 512);
  const float4* lr = (const float4*)(lw + (size_t)c * 512);
  float acc = 0.f;
#pragma unroll 4
  for (int d = 0; d < 128; ++d) {
    float4 a = wr[d], q = lr[d];
    acc += a.x * q.x + a.y * q.y + a.z * q.z + a.w * q.w;
  }
  s[b * 512 + c] = acc * RS512 + lb[c];
}

// ---------------- K2: wsq[o][i] = sum_k (cw*r)^2 ; bwf = bf16 weights in FRAGMENT layout
__global__ void k_wprep(const float* __restrict__ cw, float* __restrict__ wsq,
                        bf16_t* __restrict__ bwf) {
  int idx = blockIdx.x * 256 + threadIdx.x;  // o*512 + i
  int o = idx >> 9, i = idx & 511;
  float v[9];
  float ss = 0.f;
#pragma unroll
  for (int t = 0; t < 9; ++t) {
    float x = cw[(size_t)idx * 9 + t] * RS4608;
    v[t] = x;
    ss += x * x;
  }
  wsq[idx] = ss;
  int lane = (o & 15) | (((i >> 3) & 3) << 4);
  int base_blk = (i >> 5) * 32 + (o >> 4);  // c32*32 + fo
#pragma unroll
  for (int t = 0; t < 9; ++t) {
    size_t e = ((size_t)(t * 512 + base_blk) << 9) + lane * 8 + (i & 7);
    bwf[e] = (bf16_t)v[t];
  }
}

// ---------------- K3: sigma_inv[b][o] = rsqrt( sum_i s[b,i]^2 * wsq[o,i] + eps )
__global__ void k_sigma(const float* __restrict__ s, const float* __restrict__ wsq,
                        float* __restrict__ sinv) {
  __shared__ float s2[512];
  int b = blockIdx.y;
  int o = blockIdx.x * 256 + threadIdx.x;
  for (int i = threadIdx.x; i < 512; i += 256) {
    float v = s[b * 512 + i];
    s2[i] = v * v;
  }
  __syncthreads();
  const float4* qr = (const float4*)(wsq + (size_t)o * 512);
  float acc = 0.f;
#pragma unroll 4
  for (int d = 0; d < 128; ++d) {
    float4 q = qr[d];
    acc += q.x * s2[4 * d] + q.y * s2[4 * d + 1] + q.z * s2[4 * d + 2] + q.w * s2[4 * d + 3];
  }
  sinv[b * 512 + o] = rsqrtf(acc + 1e-8f);
}

// ---------------- K4: xt[b][h][w][ch] = bf16( x[b][ch][h][w] * s[b][ch] ), 8-ch groups
// within each 32-ch chunk XOR-permuted by ((w>>1)&3) so k_conv's ds_read is conflict-free.
__global__ void k_xt(const float* __restrict__ x, const float* __restrict__ s,
                     bf16_t* __restrict__ xt) {
  int ic = blockIdx.x, h = blockIdx.y, b = blockIdx.z;
  __shared__ __align__(16) bf16_t tile[8192];
  int t = threadIdx.x;
  int wcol = t & 63;
  int g = t >> 6;
#pragma unroll
  for (int blk = 0; blk < 4; ++blk) {
    int grp = blk * 4 + g;
    bf16x8 vec;
#pragma unroll
    for (int k = 0; k < 8; ++k) {
      int i = ic * 128 + grp * 8 + k;
      float v = x[(((size_t)b * 512 + i) * 64 + h) * 64 + wcol] * s[b * 512 + i];
      vec[k] = (bf16_t)v;
    }
    int chunk = grp ^ (wcol & 15);
    *(bf16x8*)((char*)tile + wcol * 256 + chunk * 16) = vec;
  }
  __syncthreads();
#pragma unroll
  for (int j = 0; j < 4; ++j) {
    int flat = j * 256 + t;
    int wo = flat >> 4, ig8 = flat & 15;
    int chunk = ig8 ^ (wo & 15);
    bf16x8 v = *(bf16x8*)((char*)tile + wo * 256 + chunk * 16);
    int c32 = (ig8 >> 2);
    int slot = (ig8 & 3) ^ ((wo >> 1) & 3);
    *(bf16x8*)(xt + (((size_t)b * 64 + h) * 64 + wo) * 512 + ic * 128 + c32 * 32 + slot * 8) = v;
  }
}

// ---------------- K5: implicit-GEMM conv; 3-tap ky-group phases; 8-wave single block/CU
#define AS1 __attribute__((address_space(1)))
#define AS3 __attribute__((address_space(3)))

__device__ __forceinline__ void gl16(const void* g, void* l) {
  __builtin_amdgcn_global_load_lds((const AS1 void*)g, (AS3 void*)l, 16, 0, 0);
}

#define VMCNT(n) asm volatile("s_waitcnt vmcnt(" #n ")" ::: "memory")

// LDS map: W[3 group-bufs][3 taps][8 frags][1KB] @0..73727
//          X[2 bufs][10 rows][4096B] @73728..155647 ; dummy scratch 1KB @155648
__global__ __launch_bounds__(512, 1) void k_conv(
    const bf16_t* __restrict__ xt, const bf16_t* __restrict__ bwf,
    const float* __restrict__ sinv, const float* __restrict__ noise,
    const float* __restrict__ snz, const float* __restrict__ bias,
    float* __restrict__ out) {
  __shared__ __align__(16) char lds[156672];

  const int t = threadIdx.x;
  const int rq = blockIdx.x;        // output rows h0..h0+7
  const int OY = blockIdx.y;        // o0 = OY*128
  const int b = blockIdx.z;
  const int h0 = rq * 8;
  const int lane = t & 63;
  const int wv = t >> 6;            // 8 waves
  const int wm = wv & 1;            // o-offset wm*64
  const int wn = wv >> 1;           // rows h0+wn*2 .. +1 (plus ni>>2, ky)

  const char* xtb = (const char*)xt + (size_t)b * 4194304;
  const char* xg = xtb + (lane >> 2) * 1024 + (lane & 3) * 16;
  const char* wg = (const char*)bwf + OY * 8192 + lane * 16;

  f32x4 acc[4][8] = {};

  // ---- wave-uniform staging offsets -> SGPRs (readfirstlane) ----
  uint32_t xsrcOff[5], xdstOff[5], xadd[5];
#pragma unroll
  for (int j = 0; j < 5; ++j) {
    int fl = wv * 5 + j, row = fl >> 2, q = fl & 3;
    int gr = h0 - 1 + row;
    int v = ((unsigned)gr < 64u) ? 1 : 0;
    xsrcOff[j] = __builtin_amdgcn_readfirstlane(v ? (uint32_t)(gr * 65536 + q * 16384) : 0u);
    xdstOff[j] = __builtin_amdgcn_readfirstlane(
        v ? (uint32_t)(73728 + row * 4096 + q * 1024) : 155648u);
    xadd[j] = __builtin_amdgcn_readfirstlane(v ? 40960u : 0u);
  }
  uint32_t wsrcOff[3], wdstOff[3];
#pragma unroll
  for (int k = 0; k < 3; ++k) {
    int fl = wv * 3 + k, tp = fl >> 3, fr = fl & 7;
    wsrcOff[k] = __builtin_amdgcn_readfirstlane((uint32_t)(tp * 524288 + fr * 1024));
    wdstOff[k] = __builtin_amdgcn_readfirstlane((uint32_t)(tp * 8192 + fr * 1024));
  }

  // ---- lane-dependent LDS read offsets ----
  uint32_t woffG[3];
#pragma unroll
  for (int g = 0; g < 3; ++g) woffG[g] = (uint32_t)(g * 24576 + wm * 4096 + lane * 16);
  uint32_t pX[4][3];
#pragma unroll
  for (int j = 0; j < 4; ++j)
#pragma unroll
    for (int dk = 0; dk < 3; ++dk) {
      int icol = j * 16 + (lane & 15) + dk - 1;
      int ic2 = icol < 0 ? 0 : (icol > 63 ? 63 : icol);
      int slot = (lane >> 4) ^ ((ic2 >> 1) & 3);
      pX[j][dk] = (uint32_t)(73728 + wn * 8192 + ic2 * 64 + slot * 16);
    }
  const bool c0 = (lane & 15) == 0;
  const bool c15 = (lane & 15) == 15;

  auto stX = [&](int j, uint32_t co, int bufflag) {
    gl16(xg + xsrcOff[j] + co, lds + xdstOff[j] + (bufflag ? xadd[j] : 0u));
  };
  auto stW = [&](int k, uint32_t gco, int buf) {  // gco = GP*1572864 + c*32768
    gl16(wg + wsrcOff[k] + gco, lds + wdstOff[k] + buf * 24576);
  };

  // compute one ky-group: 3 kx taps, 96 MFMA, no internal barriers
  auto comp = [&](int XB, int G) {
#pragma unroll
    for (int kx = 0; kx < 3; ++kx) {
      bf16x8 af[4];
#pragma unroll
      for (int mi = 0; mi < 4; ++mi)
        af[mi] = *(const bf16x8*)(lds + woffG[G] + (uint32_t)(kx * 8192 + mi * 1024));
      bf16x8 bfr[8];
#pragma unroll
      for (int ni = 0; ni < 8; ++ni) {
        short8 xv = *(const short8*)(lds + pX[ni & 3][kx] +
                                     (uint32_t)(XB * 40960 + ((ni >> 2) + G) * 4096));
        if (kx == 0 && (ni & 3) == 0) xv = c0 ? (short8)0 : xv;
        if (kx == 2 && (ni & 3) == 3) xv = c15 ? (short8)0 : xv;
        bfr[ni] = __builtin_bit_cast(bf16x8, xv);
      }
      __builtin_amdgcn_s_setprio(1);
#pragma unroll
      for (int mi = 0; mi < 4; ++mi)
#pragma unroll
        for (int ni = 0; ni < 8; ++ni)
          acc[mi][ni] =
              __builtin_amdgcn_mfma_f32_16x16x32_bf16(af[mi], bfr[ni], acc[mi][ni], 0, 0, 0);
      __builtin_amdgcn_s_setprio(0);
    }
  };

// one chunk = 3 ky-group phases. W buf for group G is G (gg%3==G); stage next into (G+1)%3.
// X staged for chunk c+1 at groups 1 (3 parts) and 2 (2 parts) only -- race-safe.
// vmcnt N = current group's own issue count (guarantees all prior groups' loads landed):
// interior {3,6,5}; last chunk {3,3,0}.
#define GBODY(XB, CXO, CW, LAST)                                               \
  {                                                                            \
    stW(0, 1572864u + (CW), 1); stW(1, 1572864u + (CW), 1);                    \
    stW(2, 1572864u + (CW), 1);                                                \
    VMCNT(3);                                                                  \
    __builtin_amdgcn_s_barrier();                                              \
    comp((XB), 0);                                                             \
    if (!(LAST)) {                                                             \
      stX(0, (CXO), (XB) ^ 1); stX(1, (CXO), (XB) ^ 1); stX(2, (CXO), (XB) ^ 1);\
    }                                                                          \
    stW(0, 3145728u + (CW), 2); stW(1, 3145728u + (CW), 2);                    \
    stW(2, 3145728u + (CW), 2);                                                \
    if (LAST) { VMCNT(3); } else { VMCNT(6); }                                 \
    __builtin_amdgcn_s_barrier();                                              \
    comp((XB), 1);                                                             \
    if (!(LAST)) {                                                             \
      stX(3, (CXO), (XB) ^ 1); stX(4, (CXO), (XB) ^ 1);                        \
      stW(0, (CW) + 32768u, 0); stW(1, (CW) + 32768u, 0);                      \
      stW(2, (CW) + 32768u, 0);                                                \
      VMCNT(5);                                                                \
    } else {                                                                   \
      VMCNT(0);                                                                \
    }                                                                          \
    __builtin_amdgcn_s_barrier();                                              \
    comp((XB), 2);                                                             \
  }

  // prologue: zero halo rows (edge blocks), stage X[0] + W group (0,0)
  if (rq == 0)
    *(f32x4*)(lds + 73728 + (t >> 8) * 40960 + (t & 255) * 16) = (f32x4)0.f;
  if (rq == 7)
    *(f32x4*)(lds + 73728 + (t >> 8) * 40960 + 9 * 4096 + (t & 255) * 16) = (f32x4)0.f;
  asm volatile("s_waitcnt lgkmcnt(0)" ::: "memory");
#pragma unroll
  for (int j = 0; j < 5; ++j) stX(j, 0u, 0);
  stW(0, 0u, 0); stW(1, 0u, 0); stW(2, 0u, 0);
  VMCNT(0);
  __builtin_amdgcn_s_barrier();

  uint32_t cw = 0, cxo = 64;
#pragma unroll 1
  for (int ci = 0; ci < 7; ++ci) {
    GBODY(0, cxo, cw, 0);
    cw += 32768u; cxo += 64u;
    GBODY(1, cxo, cw, 0);
    cw += 32768u; cxo += 64u;
  }
  GBODY(0, cxo, cw, 0);   // c = 14 (stages X[15], W[15,0])
  cw += 32768u;
  GBODY(1, 0u, cw, 1);    // c = 15 (LAST)

  // epilogue: demod scale + noise + bias + leaky relu
  const float* sb = sinv + b * 512;
  const int og = OY * 128 + wm * 64 + ((lane >> 4) << 2);
  const int colb = lane & 15;
  float nzv[8];
#pragma unroll
  for (int ni = 0; ni < 8; ++ni) {
    int prow = h0 + wn * 2 + (ni >> 2);
    nzv[ni] = noise[(size_t)b * 4096 + prow * 64 + (ni & 3) * 16 + colb];
  }
#pragma unroll
  for (int mi = 0; mi < 4; ++mi) {
#pragma unroll
    for (int r = 0; r < 4; ++r) {
      int o = og + mi * 16 + r;
      float sv = sb[o];
      float nw = snz[o];
      float bv = bias[o];
      float* obase = out + ((size_t)b * 512 + o) * 4096;
#pragma unroll
      for (int ni = 0; ni < 8; ++ni) {
        int prow = h0 + wn * 2 + (ni >> 2);
        int col = (ni & 3) * 16 + colb;
        float v = acc[mi][ni][r] * sv + nw * nzv[ni] + bv;
        obase[prow * 64 + col] = v > 0.f ? v : 0.2f * v;
      }
    }
  }
}

extern "C" void kernel_launch(void* const* d_in, const int* in_sizes, int n_in,
                              void* d_out, int out_size, void* d_ws, size_t ws_size,
                              hipStream_t stream) {
  const float* x     = (const float*)d_in[0];
  const float* w     = (const float*)d_in[1];
  const float* noise = (const float*)d_in[2];
  const float* lw    = (const float*)d_in[3];
  const float* lb    = (const float*)d_in[4];
  const float* cw    = (const float*)d_in[5];
  const float* snz   = (const float*)d_in[6];
  const float* bias  = (const float*)d_in[7];
  float* out = (float*)d_out;

  char* ws = (char*)d_ws;
  bf16_t* xt   = (bf16_t*)ws;                   // 67,108,864 B
  bf16_t* bwf  = (bf16_t*)(ws + 67108864);      //  4,718,592 B
  float*  s    = (float*)(ws + 71827456);       //     32,768 B
  float*  sinv = (float*)(ws + 71860224);       //     32,768 B
  float*  wsq  = (float*)(ws + 71892992);       //  1,048,576 B

  k_style<<<dim3(2, 16), 256, 0, stream>>>(w, lw, lb, s);
  k_wprep<<<dim3(1024), 256, 0, stream>>>(cw, wsq, bwf);
  k_sigma<<<dim3(2, 16), 256, 0, stream>>>(s, wsq, sinv);
  k_xt<<<dim3(4, 64, 16), 256, 0, stream>>>(x, s, xt);
  k_conv<<<dim3(8, 4, 16), 512, 0, stream>>>(xt, bwf, sinv, noise, snz, bias, out);
}

// Round 9
// 299.746 us; speedup vs baseline: 1.0764x; 1.0764x over previous
//
#include <hip/hip_runtime.h>
#include <hip/hip_bf16.h>
#include <stdint.h>

typedef __bf16 bf16_t;
typedef __bf16 bf16x8 __attribute__((ext_vector_type(8)));
typedef short short8 __attribute__((ext_vector_type(8)));
typedef float f32x4 __attribute__((ext_vector_type(4)));

#define RS512  0.044194173824159216f   // 1/sqrt(512)
#define RS4608 0.014731391274719739f   // 1/sqrt(512*9)

// ---------------- K1: style vector  s[b][c] = (w[b,:] . lw[c,:])/sqrt(512) + lb[c]
__global__ void k_style(const float* __restrict__ w, const float* __restrict__ lw,
                        const float* __restrict__ lb, float* __restrict__ s) {
  int b = blockIdx.y;
  int c = blockIdx.x * 256 + threadIdx.x;
  const float4* wr = (const float4*)(w + b * 512);
  const float4* lr = (const float4*)(lw + (size_t)c * 512);
  float acc = 0.f;
#pragma unroll 4
  for (int d = 0; d < 128; ++d) {
    float4 a = wr[d], q = lr[d];
    acc += a.x * q.x + a.y * q.y + a.z * q.z + a.w * q.w;
  }
  s[b * 512 + c] = acc * RS512 + lb[c];
}

// ---------------- K2: wsq + bf16 W fragments; also zero-fills the 4KB zero-region
__global__ void k_wprep(const float* __restrict__ cw, float* __restrict__ wsq,
                        bf16_t* __restrict__ bwf, f32x4* __restrict__ zb) {
  if (blockIdx.x == 0) zb[threadIdx.x] = (f32x4)0.f;  // 256*16B = 4KB zeros
  int idx = blockIdx.x * 256 + threadIdx.x;  // o*512 + i
  int o = idx >> 9, i = idx & 511;
  float v[9];
  float ss = 0.f;
#pragma unroll
  for (int t = 0; t < 9; ++t) {
    float x = cw[(size_t)idx * 9 + t] * RS4608;
    v[t] = x;
    ss += x * x;
  }
  wsq[idx] = ss;
  int lane = (o & 15) | (((i >> 3) & 3) << 4);
  int base_blk = (i >> 5) * 32 + (o >> 4);  // c32*32 + fo
#pragma unroll
  for (int t = 0; t < 9; ++t) {
    size_t e = ((size_t)(t * 512 + base_blk) << 9) + lane * 8 + (i & 7);
    bwf[e] = (bf16_t)v[t];
  }
}

// ---------------- K3: sigma_inv[b][o] = rsqrt( sum_i s[b,i]^2 * wsq[o,i] + eps )
__global__ void k_sigma(const float* __restrict__ s, const float* __restrict__ wsq,
                        float* __restrict__ sinv) {
  __shared__ float s2[512];
  int b = blockIdx.y;
  int o = blockIdx.x * 256 + threadIdx.x;
  for (int i = threadIdx.x; i < 512; i += 256) {
    float v = s[b * 512 + i];
    s2[i] = v * v;
  }
  __syncthreads();
  const float4* qr = (const float4*)(wsq + (size_t)o * 512);
  float acc = 0.f;
#pragma unroll 4
  for (int d = 0; d < 128; ++d) {
    float4 q = qr[d];
    acc += q.x * s2[4 * d] + q.y * s2[4 * d + 1] + q.z * s2[4 * d + 2] + q.w * s2[4 * d + 3];
  }
  sinv[b * 512 + o] = rsqrtf(acc + 1e-8f);
}

// ---------------- K4: xt[b][h][w][ch] = bf16( x[b][ch][h][w] * s[b][ch] ), slot-permuted
__global__ void k_xt(const float* __restrict__ x, const float* __restrict__ s,
                     bf16_t* __restrict__ xt) {
  int ic = blockIdx.x, h = blockIdx.y, b = blockIdx.z;
  __shared__ __align__(16) bf16_t tile[8192];
  int t = threadIdx.x;
  int wcol = t & 63;
  int g = t >> 6;
#pragma unroll
  for (int blk = 0; blk < 4; ++blk) {
    int grp = blk * 4 + g;
    bf16x8 vec;
#pragma unroll
    for (int k = 0; k < 8; ++k) {
      int i = ic * 128 + grp * 8 + k;
      float v = x[(((size_t)b * 512 + i) * 64 + h) * 64 + wcol] * s[b * 512 + i];
      vec[k] = (bf16_t)v;
    }
    int chunk = grp ^ (wcol & 15);
    *(bf16x8*)((char*)tile + wcol * 256 + chunk * 16) = vec;
  }
  __syncthreads();
#pragma unroll
  for (int j = 0; j < 4; ++j) {
    int flat = j * 256 + t;
    int wo = flat >> 4, ig8 = flat & 15;
    int chunk = ig8 ^ (wo & 15);
    bf16x8 v = *(bf16x8*)((char*)tile + wo * 256 + chunk * 16);
    int c32 = (ig8 >> 2);
    int slot = (ig8 & 3) ^ ((wo >> 1) & 3);
    *(bf16x8*)(xt + (((size_t)b * 64 + h) * 64 + wo) * 512 + ic * 128 + c32 * 32 + slot * 8) = v;
  }
}

// ---------------- K5: implicit-GEMM conv; pair-merged phases (81 barriers), counted vmcnt
#define AS1 __attribute__((address_space(1)))
#define AS3 __attribute__((address_space(3)))

__device__ __forceinline__ void gl16(const void* g, void* l) {
  __builtin_amdgcn_global_load_lds((const AS1 void*)g, (AS3 void*)l, 16, 0, 0);
}

#define VMCNT(n) asm volatile("s_waitcnt vmcnt(" #n ")" ::: "memory")
#define BAR __builtin_amdgcn_s_barrier()

// LDS map: W[2 pair-bufs][2 taps][8192B] @0..32767 ; X[2 bufs][6 rows][4096B] @32768..81919
__global__ __launch_bounds__(256, 2) void k_conv(
    const bf16_t* __restrict__ xt, const bf16_t* __restrict__ bwf,
    const float* __restrict__ sinv, const float* __restrict__ noise,
    const float* __restrict__ snz, const float* __restrict__ bias,
    const char* __restrict__ zb, float* __restrict__ out) {
  __shared__ __align__(16) char lds[81920];

  const int t = threadIdx.x;
  const int rq = blockIdx.x;        // output rows h0..h0+3
  const int OY = blockIdx.y;        // o0 = OY*128
  const int b = blockIdx.z;
  const int h0 = rq * 4;
  const int lane = t & 63;
  const int wv = t >> 6;
  const int wm = wv >> 1;           // o-offset wm*64
  const int wn = wv & 1;            // rows h0+wn*2 .. +1

  // persistent byte-based staging pointers
  const char* xg = (const char*)xt + (size_t)b * 4194304 + (t >> 2) * 1024 + (t & 3) * 16;
  const char* wgp = (const char*)bwf + OY * 8192 + wv * 2048 + lane * 16;
  const char* zgv = zb + t * 16;

  f32x4 acc[4][8] = {};

  // LDS read offsets
  const uint32_t woff = (uint32_t)((wm << 12) + (lane << 4));  // within an 8KB tap slab
  uint32_t pX[4][3];
#pragma unroll
  for (int j = 0; j < 4; ++j)
#pragma unroll
    for (int dk = 0; dk < 3; ++dk) {
      int icol = j * 16 + (lane & 15) + dk - 1;
      int ic2 = icol < 0 ? 0 : (icol > 63 ? 63 : icol);
      int slot = (lane >> 4) ^ ((ic2 >> 1) & 3);
      pX[j][dk] = (uint32_t)(32768 + wn * 8192 + ic2 * 64 + slot * 16);
    }
  const bool c0 = (lane & 15) == 0;
  const bool c15 = (lane & 15) == 15;

  auto stW = [&](uint32_t srcoff, uint32_t dst) {  // one 8KB tap slab: 2 gl16/thread
    const char* s0 = wgp + srcoff;
    gl16(s0, lds + dst + (wv << 11));
    gl16(s0 + 1024, lds + dst + (wv << 11) + 1024);
  };
  auto stX = [&](int r, uint32_t cxoff, int xb) {  // one 4KB row: 1 gl16/thread
    int gr = h0 - 1 + r;
    char* d = lds + 32768 + xb * 24576 + r * 4096 + (wv << 10);
    if ((unsigned)gr < 64u) gl16(xg + (size_t)gr * 65536 + cxoff, d);
    else gl16(zgv, d);  // real zeros from the zero-region (uniform vmem count)
  };

  auto CT = [&](int XB, int tap, uint32_t WS) {  // one tap: 12 ds_read + 32 MFMA
    const int ky = tap / 3, kx = tap % 3;
    bf16x8 af[4];
#pragma unroll
    for (int mi = 0; mi < 4; ++mi)
      af[mi] = *(const bf16x8*)(lds + (woff + WS) + (uint32_t)(mi * 1024));
    bf16x8 bfr[8];
#pragma unroll
    for (int ni = 0; ni < 8; ++ni) {
      short8 xv = *(const short8*)(lds + pX[ni & 3][kx] +
                                   (uint32_t)(XB * 24576 + ((ni >> 2) + ky) * 4096));
      if (kx == 0 && (ni & 3) == 0) xv = c0 ? (short8)0 : xv;
      if (kx == 2 && (ni & 3) == 3) xv = c15 ? (short8)0 : xv;
      bfr[ni] = __builtin_bit_cast(bf16x8, xv);
    }
    __builtin_amdgcn_s_setprio(1);
#pragma unroll
    for (int mi = 0; mi < 4; ++mi)
#pragma unroll
      for (int ni = 0; ni < 8; ++ni)
        acc[mi][ni] =
            __builtin_amdgcn_mfma_f32_16x16x32_bf16(af[mi], bfr[ni], acc[mi][ni], 0, 0, 0);
    __builtin_amdgcn_s_setprio(0);
  };

// 2-chunk unit = 9 phases. Pair j (taps 2j,2j+1 of the unit's 18-tap stream) lives in
// W buf wA (j even) / wB (j odd); phase j computes pair j and stages pair j+1.
// X: rows of c+1 staged ph0-2 (-> buf1), rows of c+2 staged ph5-7 (-> buf0).
// vmcnt ledger {2,2,2,0,0,2,2,2,0}: N=0 drains only loads with >=1-phase/compute cover.
#define UNIT(CWB, CXB, WA, WB, LAST)                                           \
  {                                                                            \
    stW((CWB) + 2u * 524288u, (WB)); stW((CWB) + 3u * 524288u, (WB) + 8192u);  \
    stX(0, (CXB), 1); stX(1, (CXB), 1);                                        \
    CT(0, 0, (WA)); CT(0, 1, (WA) + 8192u);                                    \
    VMCNT(2); BAR;                                                             \
    stW((CWB) + 4u * 524288u, (WA)); stW((CWB) + 5u * 524288u, (WA) + 8192u);  \
    stX(2, (CXB), 1); stX(3, (CXB), 1);                                        \
    CT(0, 2, (WB)); CT(0, 3, (WB) + 8192u);                                    \
    VMCNT(2); BAR;                                                             \
    stW((CWB) + 6u * 524288u, (WB)); stW((CWB) + 7u * 524288u, (WB) + 8192u);  \
    stX(4, (CXB), 1); stX(5, (CXB), 1);                                        \
    CT(0, 4, (WA)); CT(0, 5, (WA) + 8192u);                                    \
    VMCNT(2); BAR;                                                             \
    stW((CWB) + 8u * 524288u, (WA)); stW((CWB) + 32768u, (WA) + 8192u);        \
    CT(0, 6, (WB)); CT(0, 7, (WB) + 8192u);                                    \
    VMCNT(0); BAR;                                                             \
    stW((CWB) + 32768u + 1u * 524288u, (WB));                                  \
    stW((CWB) + 32768u + 2u * 524288u, (WB) + 8192u);                          \
    CT(0, 8, (WA)); CT(1, 0, (WA) + 8192u);                                    \
    VMCNT(0); BAR;                                                             \
    stW((CWB) + 32768u + 3u * 524288u, (WA));                                  \
    stW((CWB) + 32768u + 4u * 524288u, (WA) + 8192u);                          \
    if (!(LAST)) { stX(0, (CXB) + 64u, 0); stX(1, (CXB) + 64u, 0); }           \
    CT(1, 1, (WB)); CT(1, 2, (WB) + 8192u);                                    \
    if (LAST) { VMCNT(0); } else { VMCNT(2); }                                 \
    BAR;                                                                       \
    stW((CWB) + 32768u + 5u * 524288u, (WB));                                  \
    stW((CWB) + 32768u + 6u * 524288u, (WB) + 8192u);                          \
    if (!(LAST)) { stX(2, (CXB) + 64u, 0); stX(3, (CXB) + 64u, 0); }           \
    CT(1, 3, (WA)); CT(1, 4, (WA) + 8192u);                                    \
    if (LAST) { VMCNT(0); } else { VMCNT(2); }                                 \
    BAR;                                                                       \
    stW((CWB) + 32768u + 7u * 524288u, (WA));                                  \
    stW((CWB) + 32768u + 8u * 524288u, (WA) + 8192u);                          \
    if (!(LAST)) { stX(4, (CXB) + 64u, 0); stX(5, (CXB) + 64u, 0); }           \
    CT(1, 5, (WB)); CT(1, 6, (WB) + 8192u);                                    \
    if (LAST) { VMCNT(0); } else { VMCNT(2); }                                 \
    BAR;                                                                       \
    if (!(LAST)) {                                                             \
      stW((CWB) + 65536u, (WB)); stW((CWB) + 65536u + 524288u, (WB) + 8192u);  \
    }                                                                          \
    CT(1, 7, (WA)); CT(1, 8, (WA) + 8192u);                                    \
    if (!(LAST)) { VMCNT(0); BAR; }                                            \
  }

  // prologue: X[0] (zeros for halo rows) + W pair0 -> buf0
#pragma unroll
  for (int r = 0; r < 6; ++r) stX(r, 0u, 0);
  stW(0u, 0u); stW(524288u, 8192u);
  VMCNT(0); BAR;

  uint32_t cwb = 0, cxb = 64;
#pragma unroll 1
  for (int k = 0; k < 7; ++k) {
    const uint32_t wA = (uint32_t)(k & 1) << 14;  // 0 or 16384
    const uint32_t wB = wA ^ 16384u;
    UNIT(cwb, cxb, wA, wB, 0);
    cwb += 65536u; cxb += 128u;
  }
  UNIT(cwb, cxb, 16384u, 0u, 1);  // unit 7 (chunks 14,15), PW=1, LAST

  // epilogue: demod scale + noise + bias + leaky relu
  const float* sb = sinv + b * 512;
  const int og = OY * 128 + wm * 64 + ((lane >> 4) << 2);
  const int colb = lane & 15;
  float nzv[8];
#pragma unroll
  for (int ni = 0; ni < 8; ++ni) {
    int prow = h0 + wn * 2 + (ni >> 2);
    nzv[ni] = noise[(size_t)b * 4096 + prow * 64 + (ni & 3) * 16 + colb];
  }
#pragma unroll
  for (int mi = 0; mi < 4; ++mi) {
#pragma unroll
    for (int r = 0; r < 4; ++r) {
      int o = og + mi * 16 + r;
      float sv = sb[o];
      float nw = snz[o];
      float bv = bias[o];
      float* obase = out + ((size_t)b * 512 + o) * 4096;
#pragma unroll
      for (int ni = 0; ni < 8; ++ni) {
        int prow = h0 + wn * 2 + (ni >> 2);
        int col = (ni & 3) * 16 + colb;
        float v = acc[mi][ni][r] * sv + nw * nzv[ni] + bv;
        obase[prow * 64 + col] = v > 0.f ? v : 0.2f * v;
      }
    }
  }
}

extern "C" void kernel_launch(void* const* d_in, const int* in_sizes, int n_in,
                              void* d_out, int out_size, void* d_ws, size_t ws_size,
                              hipStream_t stream) {
  const float* x     = (const float*)d_in[0];
  const float* w     = (const float*)d_in[1];
  const float* noise = (const float*)d_in[2];
  const float* lw    = (const float*)d_in[3];
  const float* lb    = (const float*)d_in[4];
  const float* cw    = (const float*)d_in[5];
  const float* snz   = (const float*)d_in[6];
  const float* bias  = (const float*)d_in[7];
  float* out = (float*)d_out;

  char* ws = (char*)d_ws;
  bf16_t* xt   = (bf16_t*)ws;                   // 67,108,864 B
  bf16_t* bwf  = (bf16_t*)(ws + 67108864);      //  4,718,592 B
  float*  s    = (float*)(ws + 71827456);       //     32,768 B
  float*  sinv = (float*)(ws + 71860224);       //     32,768 B
  float*  wsq  = (float*)(ws + 71892992);       //  1,048,576 B
  char*   zbuf = ws + 72941568;                 //      4,096 B zeros

  k_style<<<dim3(2, 16), 256, 0, stream>>>(w, lw, lb, s);
  k_wprep<<<dim3(1024), 256, 0, stream>>>(cw, wsq, bwf, (f32x4*)zbuf);
  k_sigma<<<dim3(2, 16), 256, 0, stream>>>(s, wsq, sinv);
  k_xt<<<dim3(4, 64, 16), 256, 0, stream>>>(x, s, xt);
  k_conv<<<dim3(16, 4, 16), 256, 0, stream>>>(xt, bwf, sinv, noise, snz, bias, zbuf, out);
}